// Round 10
// baseline (450.759 us; speedup 1.0000x reference)
//
#include <hip/hip_runtime.h>
#include <math.h>

typedef float f4 __attribute__((ext_vector_type(4)));
typedef float f32x4 __attribute__((ext_vector_type(4)));
typedef short s8 __attribute__((ext_vector_type(8)));  // 8 bf16 (4 VGPRs)
typedef short s4 __attribute__((ext_vector_type(4)));  // 4 bf16 (2 VGPRs)

static constexpr int N = 50000;
static constexpr int E = 800000;
static constexpr int D = 128;
static constexpr int SCAN_NB = (N + 255) / 256;        // 196
static constexpr int MBLK = 64;                        // gemm rows/block
static constexpr int GRID_M = (N + MBLK - 1) / MBLK;   // 782
static constexpr int N_PAD = GRID_M * MBLK;            // 50048
static constexpr int WT_PITCH = 136;                   // LDS pad

__device__ inline unsigned short f32_bf16_rne(float x) {
    unsigned u = __float_as_uint(x);
    return (unsigned short)((u + 0x7FFF + ((u >> 16) & 1)) >> 16);
}
__device__ inline float bf16_f32(unsigned short h) {
    return __uint_as_float((unsigned)h << 16);
}

// --- int degree histogram ---
__global__ void deg_kernel(const int* __restrict__ src, const int* __restrict__ dst,
                           int* __restrict__ deg_out, int* __restrict__ deg_in) {
    int e = blockIdx.x * 256 + threadIdx.x;
    if (e < E) {
        atomicAdd(&deg_out[src[e]], 1);
        atomicAdd(&deg_in[dst[e]], 1);
    }
}

// --- scan pass 1 (+ fused norm): block sums of BOTH deg_in and deg_out ---
__global__ __launch_bounds__(256) void scan_bsum_norm_kernel(
    const int* __restrict__ deg_out, const int* __restrict__ deg_in,
    float* __restrict__ norm_src, float* __restrict__ norm_dst,
    int* __restrict__ bsums_in, int* __restrict__ bsums_out) {
    int i = blockIdx.x * 256 + threadIdx.x;
    int vi = 0, vo = 0;
    if (i < N) {
        int dgo = deg_out[i], dgi = deg_in[i];
        norm_src[i] = rsqrtf(fmaxf((float)dgo, 1.0f));
        norm_dst[i] = rsqrtf(fmaxf((float)dgi, 1.0f));
        vi = dgi;
        vo = dgo;
    }
#pragma unroll
    for (int off = 1; off < 64; off <<= 1) {
        vi += __shfl_xor(vi, off, 64);
        vo += __shfl_xor(vo, off, 64);
    }
    __shared__ int wsi[4], wso[4];
    if ((threadIdx.x & 63) == 0) {
        wsi[threadIdx.x >> 6] = vi;
        wso[threadIdx.x >> 6] = vo;
    }
    __syncthreads();
    if (threadIdx.x == 0) {
        bsums_in[blockIdx.x] = wsi[0] + wsi[1] + wsi[2] + wsi[3];
        bsums_out[blockIdx.x] = wso[0] + wso[1] + wso[2] + wso[3];
    }
}

// --- scan pass 2: exclusive scan of block sums (1 block) ---
__global__ __launch_bounds__(256) void scan_bsums_kernel(int* __restrict__ bsums) {
    __shared__ int s[256];
    int t = threadIdx.x;
    s[t] = (t < SCAN_NB) ? bsums[t] : 0;
    __syncthreads();
    for (int off = 1; off < 256; off <<= 1) {
        int v = (t >= off) ? s[t - off] : 0;
        __syncthreads();
        s[t] += v;
        __syncthreads();
    }
    if (t < SCAN_NB) bsums[t] = (t == 0) ? 0 : s[t - 1];
}

// --- scan pass 3: rescan + block offset -> ptr[] ---
__global__ __launch_bounds__(256) void scan_final_kernel(const int* __restrict__ deg,
                                                         const int* __restrict__ bsums,
                                                         int* __restrict__ ptr) {
    __shared__ int s[256];
    int b = blockIdx.x, t = threadIdx.x;
    int i = b * 256 + t;
    s[t] = (i < N) ? deg[i] : 0;
    __syncthreads();
    for (int off = 1; off < 256; off <<= 1) {
        int v = (t >= off) ? s[t - off] : 0;
        __syncthreads();
        s[t] += v;
        __syncthreads();
    }
    if (i < N) ptr[i + 1] = s[t] + bsums[b];
    if (i == 0) ptr[0] = 0;
}

// --- fill pass A: scatter edges into src-major order ---
__global__ void fill_a_kernel(const int* __restrict__ src, const int* __restrict__ dst,
                              const int* __restrict__ srow_ptr, int* __restrict__ scursor,
                              int* __restrict__ ssrc, int* __restrict__ sdst) {
    int e = blockIdx.x * 256 + threadIdx.x;
    if (e < E) {
        int s = src[e];
        int spos = srow_ptr[s] + atomicAdd(&scursor[s], 1);
        ssrc[spos] = s;
        sdst[spos] = dst[e];
    }
}

// --- fill pass B: iterate src-sorted entries, append to dst-CSR.
// Because i ascends with src, each dst segment ends up ~sorted by src ->
// concurrent agg waves walk the hs table in a narrow moving band (L2 locality).
__global__ void fill_b_kernel(const int* __restrict__ ssrc, const int* __restrict__ sdst,
                              const int* __restrict__ row_ptr, int* __restrict__ cursor,
                              int* __restrict__ csr_src) {
    int i = blockIdx.x * 256 + threadIdx.x;
    if (i < E) {
        int d = sdst[i];
        int pos = row_ptr[d] + atomicAdd(&cursor[d], 1);
        csr_src[pos] = ssrc[i];
    }
}

// --- hs[i] = emb[batch[i]] * norm_src[i] ---
__global__ void gather_kernel(const int* __restrict__ batch, const float* __restrict__ emb,
                              const float* __restrict__ norm_src, float* __restrict__ hs) {
    int gid = blockIdx.x * 256 + threadIdx.x;
    int i = gid >> 5;
    int c = (gid & 31) << 2;
    if (i < N) {
        float s = norm_src[i];
        f4 v = *(const f4*)(emb + (size_t)batch[i] * D + c);
        *(f4*)(hs + (size_t)i * D + c) = v * s;
    }
}

// --- agg: 1 wave/node, 2 edge-groups x 8-deep, full 128-col row; bf16 hi/lo out ---
__global__ void agg_kernel(const int* __restrict__ row_ptr, const int* __restrict__ csr_src,
                           const float* __restrict__ hs,
                           short* __restrict__ agg_h, short* __restrict__ agg_l) {
    int gid = blockIdx.x * 256 + threadIdx.x;
    int node = gid >> 6;
    if (node >= N) return;
    int lane = threadIdx.x & 63;
    int grp = lane >> 5;
    int col = (lane & 31) << 2;
    int beg = row_ptr[node], end = row_ptr[node + 1];

    f4 a0 = (f4)0.0f, a1 = (f4)0.0f, a2 = (f4)0.0f, a3 = (f4)0.0f;
    f4 a4 = (f4)0.0f, a5 = (f4)0.0f, a6 = (f4)0.0f, a7 = (f4)0.0f;
    int e = beg + grp;
    for (; e + 14 < end; e += 16) {
        int s0 = csr_src[e];
        int s1 = csr_src[e + 2];
        int s2 = csr_src[e + 4];
        int s3 = csr_src[e + 6];
        int s4 = csr_src[e + 8];
        int s5 = csr_src[e + 10];
        int s6 = csr_src[e + 12];
        int s7 = csr_src[e + 14];
        a0 += *(const f4*)(hs + (size_t)s0 * D + col);
        a1 += *(const f4*)(hs + (size_t)s1 * D + col);
        a2 += *(const f4*)(hs + (size_t)s2 * D + col);
        a3 += *(const f4*)(hs + (size_t)s3 * D + col);
        a4 += *(const f4*)(hs + (size_t)s4 * D + col);
        a5 += *(const f4*)(hs + (size_t)s5 * D + col);
        a6 += *(const f4*)(hs + (size_t)s6 * D + col);
        a7 += *(const f4*)(hs + (size_t)s7 * D + col);
    }
    for (; e < end; e += 2)
        a0 += *(const f4*)(hs + (size_t)csr_src[e] * D + col);
    a0 += a1; a2 += a3; a4 += a5; a6 += a7;
    a0 += a2; a4 += a6;
    a0 += a4;

    f4 o;
#pragma unroll
    for (int j = 0; j < 4; ++j)
        o[j] = a0[j] + __shfl_xor(a0[j], 32, 64);
    if (grp == 0) {
        s4 oh, ol;
#pragma unroll
        for (int j = 0; j < 4; ++j) {
            unsigned short h = f32_bf16_rne(o[j]);
            oh[j] = (short)h;
            ol[j] = (short)f32_bf16_rne(o[j] - bf16_f32(h));
        }
        *(s4*)(agg_h + (size_t)node * D + col) = oh;
        *(s4*)(agg_l + (size_t)node * D + col) = ol;
    }
}

// --- W prep: wt[layer][hi/lo][n][k] = bf16 split of W[k][n] (transposed, n-major) ---
__global__ void wprep_kernel(const float* __restrict__ W1, const float* __restrict__ W2,
                             const float* __restrict__ W3, short* __restrict__ wt) {
    int idx = blockIdx.x * 256 + threadIdx.x;
    if (idx >= 3 * D * D) return;
    int l = idx >> 14;
    int e = idx & (D * D - 1);
    int n = e >> 7, k = e & 127;
    const float* W = (l == 0) ? W1 : ((l == 1) ? W2 : W3);
    float w = W[(size_t)k * D + n];
    unsigned short h = f32_bf16_rne(w);
    unsigned short lo = f32_bf16_rne(w - bf16_f32(h));
    wt[(size_t)l * 2 * D * D + (size_t)n * D + k] = (short)h;
    wt[(size_t)l * 2 * D * D + D * D + (size_t)n * D + k] = (short)lo;
}

// --- MFMA GEMM: full 128 cols per block; 64 rows; 4 waves (16 rows each).
// 3-term split: C = Ah@Wh + Al@Wh + Ah@Wl.
__global__ __launch_bounds__(256, 2) void gemm_mfma_kernel(
    const short* __restrict__ Ah, const short* __restrict__ Al,
    const short* __restrict__ wth,
    const float* __restrict__ bias, const float* __restrict__ norm_dst,
    const float* __restrict__ post, float* __restrict__ out) {
    __shared__ short wt_h[D * WT_PITCH];   // 34816 B
    __shared__ short wt_l[D * WT_PITCH];   // 34816 B

    int tid = threadIdx.x;
    const short* gh = wth;
    const short* gl = wth + (size_t)D * D;

#pragma unroll
    for (int it = 0; it < 8; ++it) {
        int c = tid + it * 256;
        int n = c >> 4, kc = c & 15;
        *(s8*)(&wt_h[n * WT_PITCH + kc * 8]) = *(const s8*)(gh + (size_t)n * D + kc * 8);
        *(s8*)(&wt_l[n * WT_PITCH + kc * 8]) = *(const s8*)(gl + (size_t)n * D + kc * 8);
    }
    __syncthreads();

    int wv = tid >> 6;
    int lane = tid & 63;
    int lg = lane >> 4;
    int lr = lane & 15;

    int arow = blockIdx.x * 64 + wv * 16 + lr;
    const short* ahp = Ah + (size_t)arow * D;
    const short* alp = Al + (size_t)arow * D;

    f32x4 acc[8];
#pragma unroll
    for (int nt = 0; nt < 8; ++nt) acc[nt] = (f32x4)0.0f;

#pragma unroll
    for (int kt = 0; kt < 4; ++kt) {
        int ko = kt * 32 + lg * 8;
        s8 ah = *(const s8*)(ahp + ko);
        s8 al = *(const s8*)(alp + ko);
#pragma unroll
        for (int nt = 0; nt < 8; ++nt) {
            int bidx = (nt * 16 + lr) * WT_PITCH + ko;
            s8 bh = *(const s8*)(&wt_h[bidx]);
            s8 bl = *(const s8*)(&wt_l[bidx]);
            acc[nt] = __builtin_amdgcn_mfma_f32_16x16x32_bf16(ah, bh, acc[nt], 0, 0, 0);
            acc[nt] = __builtin_amdgcn_mfma_f32_16x16x32_bf16(al, bh, acc[nt], 0, 0, 0);
            acc[nt] = __builtin_amdgcn_mfma_f32_16x16x32_bf16(ah, bl, acc[nt], 0, 0, 0);
        }
    }

    int r0 = blockIdx.x * 64 + wv * 16 + lg * 4;
    float nd[4], ps[4];
#pragma unroll
    for (int i = 0; i < 4; ++i) {
        int gr = r0 + i;
        nd[i] = (gr < N) ? norm_dst[gr] : 0.0f;
        ps[i] = (gr < N) ? (post ? post[gr] : 1.0f) : 0.0f;
    }
#pragma unroll
    for (int nt = 0; nt < 8; ++nt) {
        int col = nt * 16 + lr;
        float bv = bias[col];
#pragma unroll
        for (int i = 0; i < 4; ++i) {
            int gr = r0 + i;
            if (gr < N) {
                float v = fmaxf(acc[nt][i] * nd[i] + bv, 0.0f) * ps[i];
                out[(size_t)gr * D + col] = v;
            }
        }
    }
}

extern "C" void kernel_launch(void* const* d_in, const int* in_sizes, int n_in,
                              void* d_out, int out_size, void* d_ws, size_t ws_size,
                              hipStream_t stream) {
    const int*   batch = (const int*)d_in[0];
    const int*   src   = (const int*)d_in[1];
    const int*   dst   = (const int*)d_in[2];
    const float* emb   = (const float*)d_in[3];
    const float* W1    = (const float*)d_in[4];
    const float* b1    = (const float*)d_in[5];
    const float* W2    = (const float*)d_in[6];
    const float* b2    = (const float*)d_in[7];
    const float* W3    = (const float*)d_in[8];
    const float* b3    = (const float*)d_in[9];
    float* out = (float*)d_out;

    // ws layout (4B elems): norm_src[N] | norm_dst[N] | row_ptr[N+1] | csr_src[E]
    //                       | hs[N_PAD*D] | agg_h[N_PAD*D sh] | agg_l[N_PAD*D sh] | wt
    // Overlays:
    //   ssrc/sdst (E ints each) live in the hs region: last read by fill_b, before
    //   gather_kernel writes hs.
    //   deg_out/deg_in/cursor/scursor/bsums/srow_ptr live in the agg_h region:
    //   last read by fill passes, before agg layer-1 writes agg_h.
    float* norm_src  = (float*)d_ws;
    float* norm_dst  = norm_src + N;
    int*   row_ptr   = (int*)(norm_dst + N);
    int*   csr_src   = row_ptr + (N + 1);
    float* hs        = (float*)(csr_src + E) + 3;  // 16B alignment
    short* agg_h     = (short*)(hs + (size_t)N_PAD * D);
    short* agg_l     = agg_h + (size_t)N_PAD * D;
    short* wt        = agg_l + (size_t)N_PAD * D;
    int*   ssrc      = (int*)hs;            // overlay in hs region
    int*   sdst      = ssrc + E;            // overlay in hs region
    int*   deg_out   = (int*)agg_h;         // transients in agg_h region
    int*   deg_in    = deg_out + N;
    int*   cursor    = deg_in + N;
    int*   scursor   = cursor + N;
    int*   bsums_in  = scursor + N;
    int*   bsums_out = bsums_in + SCAN_NB;
    int*   srow_ptr  = bsums_out + SCAN_NB;

    hipMemsetAsync(deg_out, 0, 4 * (size_t)N * sizeof(int), stream);
    deg_kernel<<<(E + 255) / 256, 256, 0, stream>>>(src, dst, deg_out, deg_in);
    scan_bsum_norm_kernel<<<SCAN_NB, 256, 0, stream>>>(deg_out, deg_in,
                                                       norm_src, norm_dst,
                                                       bsums_in, bsums_out);
    scan_bsums_kernel<<<1, 256, 0, stream>>>(bsums_in);
    scan_bsums_kernel<<<1, 256, 0, stream>>>(bsums_out);
    scan_final_kernel<<<SCAN_NB, 256, 0, stream>>>(deg_in, bsums_in, row_ptr);
    scan_final_kernel<<<SCAN_NB, 256, 0, stream>>>(deg_out, bsums_out, srow_ptr);
    fill_a_kernel<<<(E + 255) / 256, 256, 0, stream>>>(src, dst, srow_ptr, scursor,
                                                       ssrc, sdst);
    fill_b_kernel<<<(E + 255) / 256, 256, 0, stream>>>(ssrc, sdst, row_ptr, cursor,
                                                       csr_src);
    gather_kernel<<<((size_t)N * 32 + 255) / 256, 256, 0, stream>>>(batch, emb,
                                                                    norm_src, hs);
    wprep_kernel<<<(3 * D * D + 255) / 256, 256, 0, stream>>>(W1, W2, W3, wt);

    const float* bs[3] = {b1, b2, b3};
    for (int l = 0; l < 3; ++l) {
        bool last = (l == 2);
        agg_kernel<<<((size_t)N * 64 + 255) / 256, 256, 0, stream>>>(
            row_ptr, csr_src, hs, agg_h, agg_l);
        gemm_mfma_kernel<<<GRID_M, 256, 0, stream>>>(
            agg_h, agg_l, wt + (size_t)l * 2 * D * D, bs[l], norm_dst,
            last ? nullptr : norm_src,
            last ? out : hs);
    }
}

// Round 11
// 393.169 us; speedup vs baseline: 1.1465x; 1.1465x over previous
//
#include <hip/hip_runtime.h>
#include <math.h>

typedef float f4 __attribute__((ext_vector_type(4)));
typedef float f32x4 __attribute__((ext_vector_type(4)));
typedef short s8 __attribute__((ext_vector_type(8)));  // 8 bf16 (4 VGPRs)
typedef short s4 __attribute__((ext_vector_type(4)));  // 4 bf16 (2 VGPRs)

static constexpr int N = 50000;
static constexpr int E = 800000;
static constexpr int D = 128;
static constexpr int T = 8;                        // src tiles (3.2 MB of hs each)
static constexpr int TS = (N + T - 1) / T;         // 6250 nodes per tile
static constexpr int SCAN_NB = (N + 255) / 256;    // 196
static constexpr int MBLK = 128;                   // gemm rows/block
static constexpr int GRID_M = (N + MBLK - 1) / MBLK;  // 391
static constexpr int N_PAD = GRID_M * MBLK;        // 50048
static constexpr int WT_PITCH = 136;               // LDS pad

__device__ inline unsigned short f32_bf16_rne(float x) {
    unsigned u = __float_as_uint(x);
    return (unsigned short)((u + 0x7FFF + ((u >> 16) & 1)) >> 16);
}
__device__ inline float bf16_f32(unsigned short h) {
    return __uint_as_float((unsigned)h << 16);
}

// --- histogram: deg_out[src]++ and cnt[src_tile][dst]++ ---
__global__ void hist_kernel(const int* __restrict__ src, const int* __restrict__ dst,
                            int* __restrict__ deg_out, int* __restrict__ cnt) {
    int e = blockIdx.x * 256 + threadIdx.x;
    if (e < E) {
        int s = src[e];
        int d = dst[e];
        atomicAdd(&deg_out[s], 1);
        int t = s / TS;
        atomicAdd(&cnt[t * N + d], 1);
    }
}

// --- scan pass 1 (+ fused norms): per-block sums of deg_in (= sum_t cnt) ---
__global__ __launch_bounds__(256) void scan_bsum_norm_kernel(
    const int* __restrict__ deg_out, const int* __restrict__ cnt,
    float* __restrict__ norm_src, float* __restrict__ norm_dst,
    int* __restrict__ bsums) {
    int i = blockIdx.x * 256 + threadIdx.x;
    int tot = 0;
    if (i < N) {
        int c = 0;
#pragma unroll
        for (int t = 0; t < T; ++t) c += cnt[t * N + i];
        tot = c;
        norm_src[i] = rsqrtf(fmaxf((float)deg_out[i], 1.0f));
        norm_dst[i] = rsqrtf(fmaxf((float)tot, 1.0f));
    }
    int v = tot;
#pragma unroll
    for (int off = 1; off < 64; off <<= 1) v += __shfl_xor(v, off, 64);
    __shared__ int ws[4];
    if ((threadIdx.x & 63) == 0) ws[threadIdx.x >> 6] = v;
    __syncthreads();
    if (threadIdx.x == 0) bsums[blockIdx.x] = ws[0] + ws[1] + ws[2] + ws[3];
}

// --- scan pass 2: exclusive scan of block sums (1 block) ---
__global__ __launch_bounds__(256) void scan_bsums_kernel(int* __restrict__ bsums) {
    __shared__ int s[256];
    int t = threadIdx.x;
    s[t] = (t < SCAN_NB) ? bsums[t] : 0;
    __syncthreads();
    for (int off = 1; off < 256; off <<= 1) {
        int v = (t >= off) ? s[t - off] : 0;
        __syncthreads();
        s[t] += v;
        __syncthreads();
    }
    if (t < SCAN_NB) bsums[t] = (t == 0) ? 0 : s[t - 1];
}

// --- scan pass 3: per-node base + 8-way tile prefix -> boff[9][N] ---
// boff[t][i] = start of (node i, tile t) bucket; boff[8][i] = end of node i.
__global__ __launch_bounds__(256) void scan_final_boff_kernel(
    const int* __restrict__ cnt, const int* __restrict__ bsums,
    int* __restrict__ boff) {
    __shared__ int s[256];
    int b = blockIdx.x, tid = threadIdx.x;
    int i = b * 256 + tid;
    int c[T];
    int tot = 0;
    if (i < N) {
#pragma unroll
        for (int t = 0; t < T; ++t) { c[t] = cnt[t * N + i]; tot += c[t]; }
    }
    s[tid] = tot;
    __syncthreads();
    for (int off = 1; off < 256; off <<= 1) {
        int v = (tid >= off) ? s[tid - off] : 0;
        __syncthreads();
        s[tid] += v;
        __syncthreads();
    }
    if (i < N) {
        int run = s[tid] - tot + bsums[b];   // exclusive base for node i
#pragma unroll
        for (int t = 0; t < T; ++t) {
            boff[t * N + i] = run;
            run += c[t];
        }
        boff[T * N + i] = run;
    }
}

// --- fill: scatter each edge into its (dst, src-tile) bucket ---
__global__ void fill_kernel(const int* __restrict__ src, const int* __restrict__ dst,
                            const int* __restrict__ boff, int* __restrict__ cur,
                            int* __restrict__ csr_src) {
    int e = blockIdx.x * 256 + threadIdx.x;
    if (e < E) {
        int s = src[e];
        int d = dst[e];
        int t = s / TS;
        int idx = t * N + d;
        int pos = boff[idx] + atomicAdd(&cur[idx], 1);
        csr_src[pos] = s;
    }
}

// --- hs[i] = emb[batch[i]] * norm_src[i] ---
__global__ void gather_kernel(const int* __restrict__ batch, const float* __restrict__ emb,
                              const float* __restrict__ norm_src, float* __restrict__ hs) {
    int gid = blockIdx.x * 256 + threadIdx.x;
    int i = gid >> 5;
    int c = (gid & 31) << 2;
    if (i < N) {
        float s = norm_src[i];
        f4 v = *(const f4*)(emb + (size_t)batch[i] * D + c);
        *(f4*)(hs + (size_t)i * D + c) = v * s;
    }
}

// --- agg v3: 1 wave/node, explicit src-tile loop for L2 banding.
// All resident waves sweep tiles t=0..7 in approx lockstep -> instantaneous
// hs footprint ~1-2 tiles (3-6 MB) instead of 25.6 MB.
__global__ void agg_kernel(const int* __restrict__ boff, const int* __restrict__ csr_src,
                           const float* __restrict__ hs,
                           short* __restrict__ agg_h, short* __restrict__ agg_l) {
    int gid = blockIdx.x * 256 + threadIdx.x;
    int node = gid >> 6;
    if (node >= N) return;
    int lane = threadIdx.x & 63;
    int eg = lane >> 5;                 // edge group 0/1
    int col = (lane & 31) << 2;         // f4 column slice

    int b[T + 1];
#pragma unroll
    for (int t = 0; t <= T; ++t) b[t] = boff[t * N + node];

    f4 a0 = (f4)0.0f, a1 = (f4)0.0f;
#pragma unroll
    for (int t = 0; t < T; ++t) {
        int e = b[t] + eg;
        int en = b[t + 1];
        for (; e + 2 < en; e += 4) {
            int s0 = csr_src[e];
            int s1 = csr_src[e + 2];
            a0 += *(const f4*)(hs + (size_t)s0 * D + col);
            a1 += *(const f4*)(hs + (size_t)s1 * D + col);
        }
        if (e < en)
            a0 += *(const f4*)(hs + (size_t)csr_src[e] * D + col);
    }
    a0 += a1;

    f4 o;
#pragma unroll
    for (int j = 0; j < 4; ++j)
        o[j] = a0[j] + __shfl_xor(a0[j], 32, 64);
    if (eg == 0) {
        s4 oh, ol;
#pragma unroll
        for (int j = 0; j < 4; ++j) {
            unsigned short h = f32_bf16_rne(o[j]);
            oh[j] = (short)h;
            ol[j] = (short)f32_bf16_rne(o[j] - bf16_f32(h));
        }
        *(s4*)(agg_h + (size_t)node * D + col) = oh;
        *(s4*)(agg_l + (size_t)node * D + col) = ol;
    }
}

// --- W prep: wt[layer][hi/lo][n][k] = bf16 split of W[k][n] (transposed) ---
__global__ void wprep_kernel(const float* __restrict__ W1, const float* __restrict__ W2,
                             const float* __restrict__ W3, short* __restrict__ wt) {
    int idx = blockIdx.x * 256 + threadIdx.x;
    if (idx >= 3 * D * D) return;
    int l = idx >> 14;
    int e = idx & (D * D - 1);
    int n = e >> 7, k = e & 127;
    const float* W = (l == 0) ? W1 : ((l == 1) ? W2 : W3);
    float w = W[(size_t)k * D + n];
    unsigned short h = f32_bf16_rne(w);
    unsigned short lo = f32_bf16_rne(w - bf16_f32(h));
    wt[(size_t)l * 2 * D * D + (size_t)n * D + k] = (short)h;
    wt[(size_t)l * 2 * D * D + D * D + (size_t)n * D + k] = (short)lo;
}

// --- MFMA GEMM: 128 rows x 128 cols per block; 512 thr = 8 waves (16 rows each).
// grid=391 -> single occupancy round at 2 blocks/CU. 3-term bf16 split.
__global__ __launch_bounds__(512, 2) void gemm_mfma_kernel(
    const short* __restrict__ Ah, const short* __restrict__ Al,
    const short* __restrict__ wth,
    const float* __restrict__ bias, const float* __restrict__ norm_dst,
    const float* __restrict__ post, float* __restrict__ out) {
    __shared__ short wt_h[D * WT_PITCH];   // 34816 B
    __shared__ short wt_l[D * WT_PITCH];   // 34816 B

    int tid = threadIdx.x;
    const short* gh = wth;
    const short* gl = wth + (size_t)D * D;

#pragma unroll
    for (int it = 0; it < 4; ++it) {
        int c = tid + it * 512;            // 2048 chunks of 8 shorts
        int n = c >> 4, kc = c & 15;
        *(s8*)(&wt_h[n * WT_PITCH + kc * 8]) = *(const s8*)(gh + (size_t)n * D + kc * 8);
        *(s8*)(&wt_l[n * WT_PITCH + kc * 8]) = *(const s8*)(gl + (size_t)n * D + kc * 8);
    }
    __syncthreads();

    int wv = tid >> 6;                     // 0..7
    int lane = tid & 63;
    int lg = lane >> 4;
    int lr = lane & 15;

    int arow = blockIdx.x * MBLK + wv * 16 + lr;
    const short* ahp = Ah + (size_t)arow * D;
    const short* alp = Al + (size_t)arow * D;

    f32x4 acc[8];
#pragma unroll
    for (int nt = 0; nt < 8; ++nt) acc[nt] = (f32x4)0.0f;

#pragma unroll
    for (int kt = 0; kt < 4; ++kt) {
        int ko = kt * 32 + lg * 8;
        s8 ah = *(const s8*)(ahp + ko);
        s8 al = *(const s8*)(alp + ko);
#pragma unroll
        for (int nt = 0; nt < 8; ++nt) {
            int bidx = (nt * 16 + lr) * WT_PITCH + ko;
            s8 bh = *(const s8*)(&wt_h[bidx]);
            s8 bl = *(const s8*)(&wt_l[bidx]);
            acc[nt] = __builtin_amdgcn_mfma_f32_16x16x32_bf16(ah, bh, acc[nt], 0, 0, 0);
            acc[nt] = __builtin_amdgcn_mfma_f32_16x16x32_bf16(al, bh, acc[nt], 0, 0, 0);
            acc[nt] = __builtin_amdgcn_mfma_f32_16x16x32_bf16(ah, bl, acc[nt], 0, 0, 0);
        }
    }

    int r0 = blockIdx.x * MBLK + wv * 16 + lg * 4;
    float nd[4], ps[4];
#pragma unroll
    for (int i = 0; i < 4; ++i) {
        int gr = r0 + i;
        nd[i] = (gr < N) ? norm_dst[gr] : 0.0f;
        ps[i] = (gr < N) ? (post ? post[gr] : 1.0f) : 0.0f;
    }
#pragma unroll
    for (int nt = 0; nt < 8; ++nt) {
        int col = nt * 16 + lr;
        float bv = bias[col];
#pragma unroll
        for (int i = 0; i < 4; ++i) {
            int gr = r0 + i;
            if (gr < N) {
                float v = fmaxf(acc[nt][i] * nd[i] + bv, 0.0f) * ps[i];
                out[(size_t)gr * D + col] = v;
            }
        }
    }
}

extern "C" void kernel_launch(void* const* d_in, const int* in_sizes, int n_in,
                              void* d_out, int out_size, void* d_ws, size_t ws_size,
                              hipStream_t stream) {
    const int*   batch = (const int*)d_in[0];
    const int*   src   = (const int*)d_in[1];
    const int*   dst   = (const int*)d_in[2];
    const float* emb   = (const float*)d_in[3];
    const float* W1    = (const float*)d_in[4];
    const float* b1    = (const float*)d_in[5];
    const float* W2    = (const float*)d_in[6];
    const float* b2    = (const float*)d_in[7];
    const float* W3    = (const float*)d_in[8];
    const float* b3    = (const float*)d_in[9];
    float* out = (float*)d_out;

    // ws layout (4B elems): norm_src[N] | norm_dst[N] | boff[9N] | csr_src[E]
    //                       | hs[N_PAD*D] | agg_h[N_PAD*D sh] | agg_l[N_PAD*D sh] | wt
    // Transients (deg_out[N], cnt[8N], cur[8N] = 3.4 MB) alias the agg_h region:
    // last read by fill, before agg layer-1 writes agg_h.
    float* norm_src = (float*)d_ws;
    float* norm_dst = norm_src + N;
    int*   boff     = (int*)(norm_dst + N);
    int*   csr_src  = boff + (size_t)(T + 1) * N;
    float* hs       = (float*)(csr_src + E);
    short* agg_h    = (short*)(hs + (size_t)N_PAD * D);
    short* agg_l    = agg_h + (size_t)N_PAD * D;
    short* wt       = agg_l + (size_t)N_PAD * D;
    int*   deg_out  = (int*)agg_h;     // transient
    int*   cnt      = deg_out + N;     // 8N
    int*   cur      = cnt + (size_t)T * N;  // 8N
    int*   bsums    = cur + (size_t)T * N;  // SCAN_NB

    hipMemsetAsync(deg_out, 0, (size_t)(1 + 2 * T) * N * sizeof(int), stream);
    hist_kernel<<<(E + 255) / 256, 256, 0, stream>>>(src, dst, deg_out, cnt);
    scan_bsum_norm_kernel<<<SCAN_NB, 256, 0, stream>>>(deg_out, cnt,
                                                       norm_src, norm_dst, bsums);
    scan_bsums_kernel<<<1, 256, 0, stream>>>(bsums);
    scan_final_boff_kernel<<<SCAN_NB, 256, 0, stream>>>(cnt, bsums, boff);
    fill_kernel<<<(E + 255) / 256, 256, 0, stream>>>(src, dst, boff, cur, csr_src);
    gather_kernel<<<((size_t)N * 32 + 255) / 256, 256, 0, stream>>>(batch, emb,
                                                                    norm_src, hs);
    wprep_kernel<<<(3 * D * D + 255) / 256, 256, 0, stream>>>(W1, W2, W3, wt);

    const float* bs[3] = {b1, b2, b3};
    for (int l = 0; l < 3; ++l) {
        bool last = (l == 2);
        agg_kernel<<<((size_t)N * 64 + 255) / 256, 256, 0, stream>>>(
            boff, csr_src, hs, agg_h, agg_l);
        gemm_mfma_kernel<<<GRID_M, 512, 0, stream>>>(
            agg_h, agg_l, wt + (size_t)l * 2 * D * D, bs[l], norm_dst,
            last ? nullptr : norm_src,
            last ? out : hs);
    }
}